// Round 2
// baseline (572.835 us; speedup 1.0000x reference)
//
#include <hip/hip_runtime.h>
#include <hip/hip_bf16.h>
#include <cstdint>

// GAT forward, restructured:
//   softmax rows of (a_src[i] + a_dst[j]) == softmax of a_dst[j]  (row const cancels)
//   out = relu( ((A|I) @ (w*h)) / ((A|I) @ w) ),  w_j = exp(a_dst[j] - max)
// a_dst computed in f32 as x @ (W @ phi_dst) + b.phi_dst (exp-sensitive path stays f32).
// Big GEMM done in bf16 MFMA: mask {0,1} exact in bf16; w*h quantization ~0.4% (linear path).

typedef float  f32x4 __attribute__((ext_vector_type(4)));
typedef int    i32x4 __attribute__((ext_vector_type(4)));
typedef unsigned short u16x8 __attribute__((ext_vector_type(8)));
typedef __bf16 bf16x8 __attribute__((ext_vector_type(8)));

#define N_NODES 8192
#define F_IN    512
#define F_OUT   256
#define NC      272      // padded GEMM width: 256 h-cols + 1 denom col + 15 zero pad
#define BT_LD   8192
#define SPLITK  4
#define KSPAN   2048
#define BK      32
#define NT      (KSPAN/BK)

// workspace layout (floats for the small stuff, then byte offsets)
#define V_OFF    0                    // 512 f32
#define SCAL_OFF 512                  // [0]=bias.phi_dst, [1]=global max
#define ADST_OFF 1024                 // 8192 f32
#define WV_OFF   (ADST_OFF + 8192)    // 8192 f32
#define BT_BYTE_OFF  ((WV_OFF + 8192) * 4)            // 69632, 16B aligned
#define PART_BYTE_OFF (BT_BYTE_OFF + (size_t)NC * BT_LD * 2)  // 4526080

__device__ __forceinline__ unsigned short f2bf(float f) {
  unsigned u = __builtin_bit_cast(unsigned, f);
  unsigned r = (u + 0x7FFFu + ((u >> 16) & 1u)) >> 16;
  return (unsigned short)r;
}

__device__ __forceinline__ void gload_lds16(const void* g, void* l) {
  auto gp = (const __attribute__((address_space(1))) unsigned int*)(uintptr_t)g;
  auto lp = (__attribute__((address_space(3))) unsigned int*)(uintptr_t)l;
  __builtin_amdgcn_global_load_lds(gp, lp, 16, 0, 0);
}

// ---------------- k_prep: v = W @ phi_dst ; scal[0] = bias . phi_dst ----------------
__global__ __launch_bounds__(256) void k_prep(const float* __restrict__ W,
    const float* __restrict__ bias, const float* __restrict__ phi,
    float* __restrict__ v, float* __restrict__ scal) {
  __shared__ float sp[256];
  const int t = threadIdx.x;
  sp[t] = phi[256 + t];
  __syncthreads();
  const int k = blockIdx.x * 256 + t;
  const float* wr = W + (size_t)k * F_OUT;
  float acc = 0.f;
  #pragma unroll 4
  for (int c = 0; c < 256; c += 4) {
    f32x4 w4 = *(const f32x4*)(wr + c);
    f32x4 p4 = *(const f32x4*)(&sp[c]);
    acc += w4[0]*p4[0] + w4[1]*p4[1] + w4[2]*p4[2] + w4[3]*p4[3];
  }
  v[k] = acc;
  if (blockIdx.x == 0) {
    __shared__ float sd[256];
    sd[t] = bias[t] * sp[t];
    __syncthreads();
    for (int s = 128; s > 0; s >>= 1) { if (t < s) sd[t] += sd[t + s]; __syncthreads(); }
    if (t == 0) scal[0] = sd[0];
  }
}

// ---------------- k_adst: a_dst[j] = x[j,:] . v + bias_dot (f32, one wave per row) ----
__global__ __launch_bounds__(256) void k_adst(const float* __restrict__ x,
    const float* __restrict__ v, const float* __restrict__ scal,
    float* __restrict__ adst) {
  __shared__ float sv[512];
  const int t = threadIdx.x;
  sv[t] = v[t]; sv[t + 256] = v[t + 256];
  __syncthreads();
  const int lane = t & 63, wv = t >> 6;
  const int j = blockIdx.x * 4 + wv;
  const float* xr = x + (size_t)j * F_IN;
  f32x4 xa = *(const f32x4*)(xr + lane * 4);
  f32x4 xb = *(const f32x4*)(xr + 256 + lane * 4);
  f32x4 va = *(const f32x4*)(&sv[lane * 4]);
  f32x4 vb = *(const f32x4*)(&sv[256 + lane * 4]);
  float s = xa[0]*va[0] + xa[1]*va[1] + xa[2]*va[2] + xa[3]*va[3]
          + xb[0]*vb[0] + xb[1]*vb[1] + xb[2]*vb[2] + xb[3]*vb[3];
  #pragma unroll
  for (int off = 32; off > 0; off >>= 1) s += __shfl_down(s, off);
  if (lane == 0) adst[j] = s + scal[0];
}

// ---------------- k_max: global max of a_dst -> scal[1] ----------------
__global__ __launch_bounds__(256) void k_max(const float* __restrict__ adst,
    float* __restrict__ scal) {
  __shared__ float red[4];
  const int t = threadIdx.x;
  float m = -3.4e38f;
  #pragma unroll
  for (int i = 0; i < 32; ++i) m = fmaxf(m, adst[t + i * 256]);
  const int lane = t & 63;
  #pragma unroll
  for (int off = 32; off > 0; off >>= 1) m = fmaxf(m, __shfl_down(m, off));
  if (lane == 0) red[t >> 6] = m;
  __syncthreads();
  if (t == 0) scal[1] = fmaxf(fmaxf(red[0], red[1]), fmaxf(red[2], red[3]));
}

// ---------------- k_w: w = exp(a_dst - M); also fills Bt row 256 (denominator col) ----
__global__ __launch_bounds__(256) void k_w(const float* __restrict__ adst,
    const float* __restrict__ scal, float* __restrict__ wvec,
    unsigned short* __restrict__ Bt) {
  const int j = blockIdx.x * 256 + threadIdx.x;
  const float e = __expf(adst[j] - scal[1]);
  wvec[j] = e;
  Bt[(size_t)256 * BT_LD + j] = f2bf(e);
}

// ---------------- k_h: h = x@W + b (f32), writes Bt[c][j] = bf16(w_j * h[j][c]) -------
// tile 128(j) x 64(c), BK=32, thread = 8x4 micro-tile; XOR-swizzled LDS to kill bank conflicts
__global__ __launch_bounds__(256) void k_h(const float* __restrict__ x,
    const float* __restrict__ W, const float* __restrict__ bias,
    const float* __restrict__ wvec, unsigned short* __restrict__ Bt) {
  __shared__ float sx[128][32];
  __shared__ float sw[64][32];
  const int t = threadIdx.x;
  const int ty = t & 15, tx = t >> 4;
  const int j0 = blockIdx.x * 128, c0 = blockIdx.y * 64;
  float acc[8][4];
  #pragma unroll
  for (int r = 0; r < 8; ++r)
    #pragma unroll
    for (int q = 0; q < 4; ++q) acc[r][q] = 0.f;

  for (int kt = 0; kt < F_IN / BK; ++kt) {
    const int k0 = kt * BK;
    __syncthreads();
    #pragma unroll
    for (int i = 0; i < 4; ++i) {             // x tile: 128 rows x 32 k
      int n = t + i * 256, row = n >> 3, f4 = n & 7;
      f32x4 vv = *(const f32x4*)(x + (size_t)(j0 + row) * F_IN + k0 + f4 * 4);
      *(f32x4*)&sx[row][(f4 * 4) ^ (((row >> 3) & 7) << 2)] = vv;
    }
    #pragma unroll
    for (int i = 0; i < 8; ++i) {             // W tile transposed: 64 c x 32 k
      int n = t + i * 256, k = n >> 6, c = n & 63;
      sw[c][k ^ (((c >> 2) & 7) << 2)] = W[(size_t)(k0 + k) * F_OUT + c0 + c];
    }
    __syncthreads();
    #pragma unroll
    for (int kb4 = 0; kb4 < 8; ++kb4) {
      const int kb = kb4 * 4;
      f32x4 a4[8], b4[4];
      #pragma unroll
      for (int r = 0; r < 8; ++r) { int row = ty * 8 + r;
        a4[r] = *(const f32x4*)&sx[row][kb ^ (((row >> 3) & 7) << 2)]; }
      #pragma unroll
      for (int q = 0; q < 4; ++q) { int c = tx * 4 + q;
        b4[q] = *(const f32x4*)&sw[c][kb ^ (((c >> 2) & 7) << 2)]; }
      #pragma unroll
      for (int kk = 0; kk < 4; ++kk)
        #pragma unroll
        for (int r = 0; r < 8; ++r)
          #pragma unroll
          for (int q = 0; q < 4; ++q)
            acc[r][q] = fmaf(a4[r][kk], b4[q][kk], acc[r][q]);
    }
  }
  const int jr = j0 + ty * 8;
  f32x4 w0 = *(const f32x4*)(wvec + jr);
  f32x4 w1 = *(const f32x4*)(wvec + jr + 4);
  #pragma unroll
  for (int q = 0; q < 4; ++q) {
    const int c = c0 + tx * 4 + q;
    const float bc = bias[c];
    u16x8 o;
    #pragma unroll
    for (int r = 0; r < 4; ++r) o[r]     = f2bf((acc[r][q]     + bc) * w0[r]);
    #pragma unroll
    for (int r = 0; r < 4; ++r) o[r + 4] = f2bf((acc[r + 4][q] + bc) * w1[r]);
    *(u16x8*)(Bt + (size_t)c * BT_LD + jr) = o;   // coalesced: lanes = consecutive j
  }
}

// ---------------- k_big: partial[s] = (A|I)[:, ks] @ B[ks, :]  (bf16 MFMA) ------------
// BM=64, BK=32, split-K=4. LDS k-slot-major layout -> conflict-free ds_read_b128.
// B staged via global_load_lds (16B); A staged via regs (int32 -> bf16 {0,1}, diag=1).
template<int NB>
__device__ __forceinline__ void big_body(const int* __restrict__ adj,
    const unsigned short* __restrict__ Bt, float* __restrict__ pblk,
    unsigned short (*sA)[2048], unsigned short (*sB)[8704],
    int m0, int kbase, int tid, int col_off) {
  const int lane = tid & 63;
  const int wv = tid >> 6;
  const int wm = wv >> 1;
  const int l15 = lane & 15;
  const int kq = lane >> 4;

  // A staging: thread -> (row, k-chunk of 8)
  const int arow = tid >> 2;
  const int akc = tid & 3;
  const int rowg = m0 + arow;
  const int* asrc = adj + (size_t)rowg * N_NODES + kbase + akc * 8;
  const int aldst = (akc * 64 + arow) * 8;

  // B staging: wave-chunks of 1024B; LDS slot n -> (kslot = n/272, col = n%272)
  const unsigned char* bsrc[5];
  #pragma unroll
  for (int i = 0; i < 5; ++i) {
    int q = wv + i * 4;
    if (q < 17) {
      int n = q * 64 + lane;
      int ks = n / 272;
      int col = n - ks * 272;
      bsrc[i] = (const unsigned char*)Bt + (size_t)col * (BT_LD * 2) + (size_t)kbase * 2 + ks * 16;
    } else bsrc[i] = nullptr;
  }

  f32x4 acc[2][NB];
  #pragma unroll
  for (int a = 0; a < 2; ++a)
    #pragma unroll
    for (int b = 0; b < NB; ++b) acc[a][b] = f32x4{0.f, 0.f, 0.f, 0.f};

  // prologue: stage step 0 into buf 0
  #pragma unroll
  for (int i = 0; i < 5; ++i) { int q = wv + i * 4; if (q < 17) gload_lds16(bsrc[i], &sB[0][q * 512]); }
  {
    i32x4 p0 = *(const i32x4*)(asrc);
    i32x4 p1 = *(const i32x4*)(asrc + 4);
    int d = rowg - (kbase + akc * 8);
    u16x8 vv;
    #pragma unroll
    for (int e = 0; e < 4; ++e) vv[e]     = (p0[e] != 0 || d == e)     ? (unsigned short)0x3F80 : (unsigned short)0;
    #pragma unroll
    for (int e = 0; e < 4; ++e) vv[e + 4] = (p1[e] != 0 || d == e + 4) ? (unsigned short)0x3F80 : (unsigned short)0;
    *(u16x8*)&sA[0][aldst] = vv;
  }
  __syncthreads();

  int buf = 0;
  for (int t = 0; t < NT; ++t) {
    const int nb = buf ^ 1;
    i32x4 p0, p1;
    const bool pref = (t + 1 < NT);
    if (pref) {  // issue loads early: latency hides under MFMA below (T14 split)
      #pragma unroll
      for (int i = 0; i < 5; ++i) { int q = wv + i * 4;
        if (q < 17) gload_lds16(bsrc[i] + (size_t)(t + 1) * 64, &sB[nb][q * 512]); }
      p0 = *(const i32x4*)(asrc + (t + 1) * 32);
      p1 = *(const i32x4*)(asrc + (t + 1) * 32 + 4);
    }
    bf16x8 af[2];
    #pragma unroll
    for (int a = 0; a < 2; ++a)
      af[a] = *(const bf16x8*)&sA[buf][(kq * 64 + wm * 32 + a * 16 + l15) * 8];
    #pragma unroll
    for (int b = 0; b < NB; ++b) {
      bf16x8 bb = *(const bf16x8*)&sB[buf][(kq * 272 + col_off + b * 16 + l15) * 8];
      #pragma unroll
      for (int a = 0; a < 2; ++a)
        acc[a][b] = __builtin_amdgcn_mfma_f32_16x16x32_bf16(af[a], bb, acc[a][b], 0, 0, 0);
    }
    if (pref) {
      int d = rowg - (kbase + (t + 1) * 32 + akc * 8);
      u16x8 vv;
      #pragma unroll
      for (int e = 0; e < 4; ++e) vv[e]     = (p0[e] != 0 || d == e)     ? (unsigned short)0x3F80 : (unsigned short)0;
      #pragma unroll
      for (int e = 0; e < 4; ++e) vv[e + 4] = (p1[e] != 0 || d == e + 4) ? (unsigned short)0x3F80 : (unsigned short)0;
      *(u16x8*)&sA[nb][aldst] = vv;
    }
    __syncthreads();
    buf = nb;
  }

  // epilogue: C/D layout col=lane&15, row=(lane>>4)*4+reg  [verified m89]
  // skip dead pad cols 257..271 (only col<=256 is ever read by k_fin)
  #pragma unroll
  for (int a = 0; a < 2; ++a)
    #pragma unroll
    for (int b = 0; b < NB; ++b)
      #pragma unroll
      for (int r = 0; r < 4; ++r) {
        int row = wm * 32 + a * 16 + kq * 4 + r;
        int col = col_off + b * 16 + l15;
        if (col <= 256)
          pblk[(size_t)row * NC + col] = acc[a][b][r];
      }
}

__global__ __launch_bounds__(256, 2) void k_big(const int* __restrict__ adj,
    const unsigned short* __restrict__ Bt, float* __restrict__ part) {
  __shared__ unsigned short sA[2][2048];
  __shared__ unsigned short sB[2][8704];
  const int mb = blockIdx.x, s = blockIdx.y;
  const int m0 = mb * 64, kbase = s * KSPAN;
  const int tid = threadIdx.x;
  float* pblk = part + ((size_t)s * N_NODES + m0) * NC;
  if (((tid >> 6) & 1) == 0) big_body<9>(adj, Bt, pblk, sA, sB, m0, kbase, tid, 0);
  else                       big_body<8>(adj, Bt, pblk, sA, sB, m0, kbase, tid, 144);
}

// ---------------- k_fin: out = relu( sum_s num / sum_s den ) ----------------
__global__ __launch_bounds__(256) void k_fin(const float* __restrict__ part,
    float* __restrict__ out) {
  const int i = blockIdx.x, c = threadIdx.x;
  const size_t S = (size_t)N_NODES * NC;
  const float* p = part + (size_t)i * NC;
  float num = p[c] + p[S + c] + p[2 * S + c] + p[3 * S + c];
  float den = p[256] + p[S + 256] + p[2 * S + 256] + p[3 * S + 256];
  out[(size_t)i * F_OUT + c] = fmaxf(num / den, 0.f);
}

extern "C" void kernel_launch(void* const* d_in, const int* in_sizes, int n_in,
                              void* d_out, int out_size, void* d_ws, size_t ws_size,
                              hipStream_t stream) {
  const int*   adj  = (const int*)d_in[0];
  const float* x    = (const float*)d_in[1];
  const float* W    = (const float*)d_in[2];
  const float* bias = (const float*)d_in[3];
  const float* phi  = (const float*)d_in[4];
  float* out = (float*)d_out;

  float* wsf  = (float*)d_ws;
  float* v    = wsf + V_OFF;
  float* scal = wsf + SCAL_OFF;
  float* adst = wsf + ADST_OFF;
  float* wvec = wsf + WV_OFF;
  unsigned short* Bt = (unsigned short*)((char*)d_ws + BT_BYTE_OFF);
  float* part = (float*)((char*)d_ws + PART_BYTE_OFF);

  // zero the padding rows 257..271 of Bt (col 256 = denom written by k_w)
  hipMemsetAsync(Bt + (size_t)257 * BT_LD, 0, (size_t)15 * BT_LD * 2, stream);
  k_prep<<<2, 256, 0, stream>>>(W, bias, phi, v, scal);
  k_adst<<<2048, 256, 0, stream>>>(x, v, scal, adst);
  k_max<<<1, 256, 0, stream>>>(adst, scal);
  k_w<<<32, 256, 0, stream>>>(adst, scal, wvec, Bt);
  k_h<<<dim3(64, 4), 256, 0, stream>>>(x, W, bias, wvec, Bt);
  k_big<<<dim3(128, SPLITK), 256, 0, stream>>>(adj, Bt, part);
  k_fin<<<8192, 256, 0, stream>>>(part, out);
}